// Round 13
// baseline (5038.399 us; speedup 1.0000x reference)
//
#include <hip/hip_runtime.h>
#include <math.h>

// ---------------------------------------------------------------------------
// Hierarchical bi-GRU (char bi-GRU -> word bi-GRU -> FC head), fp32.
//
// r13 = r12 (best, 4684us) with word fused GRU R=2 -> R=1: 512 blocks x 256
// threads = 2 blocks/CU. Same per-block weight stream (bf16, 1.5MB/step),
// same load widths; the second resident block's waves run while the first
// drains vmcnt(0) at its barriers (m114 implicit overlap). Total L2 traffic
// doubles to ~2.6TB/s/XCD -- affordable post-bf16, impossible in fp32 (r9).
//
//   gates = sigmoid(x@Wg_x + h@Wg_h + bg)      (x-part precomputed)
//   c     = tanh  (x@Wc_x + (r*h)@Wc_h + bc)
//   h'    = mask ? u*h + (1-u)*c : h
// ---------------------------------------------------------------------------

#define TILE 64
#define BKK 16

enum AMode { A_PLAIN = 0, A_CHARSTATE = 1, A_RH = 2, A_GATHER = 3 };
enum EMode { E_BIAS = 0, E_GATE_CHAR = 1, E_CAND_CHAR = 2, E_XW = 3 };

struct GemmArgs {
  int M, N, K;
  const float* A; int lda;
  const float* G; int ldg;
  const int*   arows;
  const float* B;
  const float* bias;
  const float* XT; int ldxt;
  const int*   seqs;
  const int*   lens;
  int t, T;
  const int*   cidx;
  const float* Hin;
  float* Cout; int ldc;
};

__device__ __forceinline__ float sigmoidf_(float x) { return 1.0f / (1.0f + expf(-x)); }
__device__ __forceinline__ float bf2f_(unsigned short u) {
  return __uint_as_float((unsigned int)u << 16);
}

template<int AM, int EM>
__global__ __launch_bounds__(256) void gemm_k(GemmArgs p) {
  __shared__ float As[BKK][TILE];
  __shared__ float Bs[BKK][TILE];
  const int tid = threadIdx.x;
  const int tx = tid & 15, ty = tid >> 4;
  const int m0 = blockIdx.y * TILE, n0 = blockIdx.x * TILE;
  const int la_r = tid >> 2, la_k = (tid & 3) << 2;
  const int lb_k = tid >> 4, lb_n = (tid & 15) << 2;

  float acc[4][4] = {};
  int arow = 0;
  if constexpr (AM == A_GATHER) arow = p.arows[m0 + la_r];

  for (int k0 = 0; k0 < p.K; k0 += BKK) {
    float4 av;
    const int m = m0 + la_r;
    const int k = k0 + la_k;
    if constexpr (AM == A_PLAIN) {
      av = *reinterpret_cast<const float4*>(p.A + (size_t)m * p.lda + k);
    } else if constexpr (AM == A_CHARSTATE) {
      const float* ap = (k < 512) ? (p.A + (size_t)m * 512 + k)
                                  : (p.A + (size_t)(2048 + m) * 512 + (k - 512));
      av = *reinterpret_cast<const float4*>(ap);
    } else if constexpr (AM == A_RH) {
      float4 g = *reinterpret_cast<const float4*>(p.G + (size_t)m * p.ldg + k);
      float4 h = *reinterpret_cast<const float4*>(p.A + (size_t)m * p.lda + k);
      av = make_float4(g.x * h.x, g.y * h.y, g.z * h.z, g.w * h.w);
    } else { // A_GATHER
      av = *reinterpret_cast<const float4*>(p.A + (size_t)arow * p.lda + k);
    }
    As[la_k + 0][la_r] = av.x;
    As[la_k + 1][la_r] = av.y;
    As[la_k + 2][la_r] = av.z;
    As[la_k + 3][la_r] = av.w;
    float4 bv = *reinterpret_cast<const float4*>(p.B + (size_t)(k0 + lb_k) * p.N + n0 + lb_n);
    *reinterpret_cast<float4*>(&Bs[lb_k][lb_n]) = bv;
    __syncthreads();
#pragma unroll
    for (int kk = 0; kk < BKK; ++kk) {
      float4 a = *reinterpret_cast<const float4*>(&As[kk][ty << 2]);
      float4 b = *reinterpret_cast<const float4*>(&Bs[kk][tx << 2]);
      acc[0][0] += a.x * b.x; acc[0][1] += a.x * b.y; acc[0][2] += a.x * b.z; acc[0][3] += a.x * b.w;
      acc[1][0] += a.y * b.x; acc[1][1] += a.y * b.y; acc[1][2] += a.y * b.z; acc[1][3] += a.y * b.w;
      acc[2][0] += a.z * b.x; acc[2][1] += a.z * b.y; acc[2][2] += a.z * b.z; acc[2][3] += a.z * b.w;
      acc[3][0] += a.w * b.x; acc[3][1] += a.w * b.y; acc[3][2] += a.w * b.z; acc[3][3] += a.w * b.w;
    }
    __syncthreads();
  }

  const int rbase = m0 + (ty << 2);
  const int cbase = n0 + (tx << 2);
#pragma unroll
  for (int i = 0; i < 4; ++i) {
    const int row = rbase + i;
    if constexpr (EM == E_BIAS) {
#pragma unroll
      for (int j = 0; j < 4; ++j) {
        const int col = cbase + j;
        p.Cout[(size_t)row * p.ldc + col] = acc[i][j] + p.bias[col];
      }
    } else if constexpr (EM == E_GATE_CHAR || EM == E_CAND_CHAR) {
      const int us = row & 2047;
      const bool dir = row >= 2048;
      const int len = p.lens[us];
      int pos = dir ? (len - 1 - p.t) : p.t;
      pos = pos < 0 ? 0 : (pos > p.T - 1 ? p.T - 1 : pos);
      const int ch = p.seqs[us * p.T + pos];
      const float* xrow = p.XT + (size_t)ch * p.ldxt;
      const bool mask = p.t < len;
#pragma unroll
      for (int j = 0; j < 4; ++j) {
        const int col = cbase + j;
        if constexpr (EM == E_GATE_CHAR) {
          p.Cout[(size_t)row * p.ldc + col] = sigmoidf_(acc[i][j] + xrow[col]);
        } else {
          const float cv = tanhf(acc[i][j] + xrow[col]);
          const float u  = p.G[(size_t)row * p.ldg + 512 + col];
          const float h  = p.Hin[(size_t)row * 512 + col];
          p.Cout[(size_t)row * p.ldc + col] = mask ? (u * h + (1.0f - u) * cv) : h;
        }
      }
    } else { // E_XW
      const int cs = p.cidx[row];
      const float* xrow = p.XT + (size_t)cs * p.ldxt;
#pragma unroll
      for (int j = 0; j < 4; ++j) {
        const int col = cbase + j;
        p.Cout[(size_t)row * p.ldc + col] = acc[i][j] + xrow[col];
      }
    }
  }
}

// fp32 -> bf16 (RNE) weight conversion
__global__ __launch_bounds__(256) void wconv_k(const float* __restrict__ src,
                                               unsigned short* __restrict__ dst,
                                               int n) {
  const int i = blockIdx.x * 256 + threadIdx.x;
  if (i < n) {
    const unsigned int u = __float_as_uint(src[i]);
    dst[i] = (unsigned short)((u + 0x7FFFu + ((u >> 16) & 1u)) >> 16);
  }
}

// ---------------------------------------------------------------------------
// Fused persistent word GRU, bf16 weights: R rows/block.
// Phase 1: thread owns 4 gate cols (ushort4 weight loads, k-step-4, float4
// LDS h-reads). Phase 2: thread owns 2 cand cols (ushort2 loads).
// Rows: [0,NU) = forward, [NU,2NU) = backward (dir uniform per block).
// r13: R=1 -> 512 blocks = 2 blocks/CU for barrier-drain overlap.
// ---------------------------------------------------------------------------
template<int R, int NU, int TT>
__global__ __launch_bounds__(256) void gru_word_bf(
    const unsigned short* __restrict__ Whg,  // [512,1024] bf16
    const unsigned short* __restrict__ Whc,  // [512,512]  bf16
    const float* __restrict__ Xg,            // [NU*TT,1024] (bias folded)
    const float* __restrict__ Xc,            // [NU*TT,512]
    const int*   __restrict__ lens,          // [NU]
    float* __restrict__ Hout)                // [2*NU, 512]
{
  __shared__ float h_s [R][512];
  __shared__ float rh_s[R][512];
  __shared__ float u_s [R][512];
  __shared__ int   xog_s[R];
  __shared__ int   xoc_s[R];
  __shared__ int   msk_s[R];

  const int tid  = threadIdx.x;
  const int row0 = blockIdx.x * R;
  const int us0  = row0 & (NU - 1);
  const bool bw  = row0 >= NU;

  for (int i = tid; i < R * 512; i += 256) h_s[i >> 9][i & 511] = 0.0f;
  int mylen = 0;
  if (tid < R) mylen = lens[us0 + tid];
  __syncthreads();

  const int c0 = tid << 2;   // phase-1: 4 gate cols of 1024
  const int c2 = tid << 1;   // phase-2: 2 cand cols of 512

  for (int t = 0; t < TT; ++t) {
    if (tid < R) {
      int pos = bw ? (mylen - 1 - t) : t;
      pos = pos < 0 ? 0 : (pos > TT - 1 ? TT - 1 : pos);
      const int xr = (us0 + tid) * TT + pos;
      xog_s[tid] = xr * 1024;
      xoc_s[tid] = xr * 512;
      msk_s[tid] = (t < mylen) ? 1 : 0;
    }
    __syncthreads();

    // ---- phase 1: gates = sigmoid(h @ Whg + Xg); rh / u -> LDS ----
    float4 acc[R];
#pragma unroll
    for (int r = 0; r < R; ++r) acc[r] = make_float4(0.f, 0.f, 0.f, 0.f);
#pragma unroll 2
    for (int k0 = 0; k0 < 512; k0 += 4) {
      ushort4 wu[4];
#pragma unroll
      for (int i = 0; i < 4; ++i)
        wu[i] = *reinterpret_cast<const ushort4*>(Whg + (size_t)(k0 + i) * 1024 + c0);
      float4 hv[R];
#pragma unroll
      for (int r = 0; r < R; ++r)
        hv[r] = *reinterpret_cast<const float4*>(&h_s[r][k0]);
#pragma unroll
      for (int i = 0; i < 4; ++i) {
        const float wx = bf2f_(wu[i].x), wy = bf2f_(wu[i].y);
        const float wz = bf2f_(wu[i].z), ww = bf2f_(wu[i].w);
#pragma unroll
        for (int r = 0; r < R; ++r) {
          const float h = (i == 0) ? hv[r].x : (i == 1) ? hv[r].y : (i == 2) ? hv[r].z : hv[r].w;
          acc[r].x += h * wx; acc[r].y += h * wy;
          acc[r].z += h * wz; acc[r].w += h * ww;
        }
      }
    }
#pragma unroll
    for (int r = 0; r < R; ++r) {
      const float4 x = *reinterpret_cast<const float4*>(Xg + xog_s[r] + c0);
      float4 g;
      g.x = sigmoidf_(acc[r].x + x.x);
      g.y = sigmoidf_(acc[r].y + x.y);
      g.z = sigmoidf_(acc[r].z + x.z);
      g.w = sigmoidf_(acc[r].w + x.w);
      if (c0 < 512) {        // r-gate cols -> rh = r * h
        const float4 hh = *reinterpret_cast<const float4*>(&h_s[r][c0]);
        rh_s[r][c0 + 0] = g.x * hh.x;
        rh_s[r][c0 + 1] = g.y * hh.y;
        rh_s[r][c0 + 2] = g.z * hh.z;
        rh_s[r][c0 + 3] = g.w * hh.w;
      } else {               // u-gate cols
        u_s[r][c0 - 512 + 0] = g.x;
        u_s[r][c0 - 512 + 1] = g.y;
        u_s[r][c0 - 512 + 2] = g.z;
        u_s[r][c0 - 512 + 3] = g.w;
      }
    }
    __syncthreads();

    // ---- phase 2: c = tanh(rh @ Whc + Xc); h' = mask ? u*h+(1-u)*c : h ----
    float2 acc2[R];
#pragma unroll
    for (int r = 0; r < R; ++r) acc2[r] = make_float2(0.f, 0.f);
#pragma unroll 2
    for (int k0 = 0; k0 < 512; k0 += 4) {
      ushort2 wu[4];
#pragma unroll
      for (int i = 0; i < 4; ++i)
        wu[i] = *reinterpret_cast<const ushort2*>(Whc + (size_t)(k0 + i) * 512 + c2);
      float4 rv[R];
#pragma unroll
      for (int r = 0; r < R; ++r)
        rv[r] = *reinterpret_cast<const float4*>(&rh_s[r][k0]);
#pragma unroll
      for (int i = 0; i < 4; ++i) {
        const float wx = bf2f_(wu[i].x), wy = bf2f_(wu[i].y);
#pragma unroll
        for (int r = 0; r < R; ++r) {
          const float rvv = (i == 0) ? rv[r].x : (i == 1) ? rv[r].y : (i == 2) ? rv[r].z : rv[r].w;
          acc2[r].x += rvv * wx; acc2[r].y += rvv * wy;
        }
      }
    }
#pragma unroll
    for (int r = 0; r < R; ++r) {
      const float2 x = *reinterpret_cast<const float2*>(Xc + xoc_s[r] + c2);
      const float cx = tanhf(acc2[r].x + x.x);
      const float cy = tanhf(acc2[r].y + x.y);
      if (msk_s[r]) {
        const float ux = u_s[r][c2], uy = u_s[r][c2 + 1];
        const float hx = h_s[r][c2], hy = h_s[r][c2 + 1];
        h_s[r][c2]     = ux * hx + (1.0f - ux) * cx;
        h_s[r][c2 + 1] = uy * hy + (1.0f - uy) * cy;
      }
    }
    __syncthreads();
  }

  for (int i = tid; i < R * 512; i += 256)
    Hout[(size_t)(row0 + (i >> 9)) * 512 + (i & 511)] = h_s[i >> 9][i & 511];
}

// FC head
__global__ __launch_bounds__(64) void head_k(const float* __restrict__ Hw,
                                             const float* __restrict__ W1,
                                             const float* __restrict__ b1,
                                             const float* __restrict__ W2,
                                             const float* __restrict__ b2,
                                             float* __restrict__ out) {
  __shared__ float s[1024];
  __shared__ float hid[64];
  const int b = blockIdx.x;
  const int tid = threadIdx.x;
  for (int k = tid; k < 512; k += 64) {
    s[k]       = Hw[(size_t)b * 512 + k];
    s[512 + k] = Hw[(size_t)(256 + b) * 512 + k];
  }
  __syncthreads();
  float acc = b1[tid];
  for (int k = 0; k < 1024; ++k) acc += s[k] * W1[k * 64 + tid];
  acc = acc > 0.0f ? acc : 0.2f * acc;
  hid[tid] = acc;
  __syncthreads();
  if (tid < 2) {
    float a = b2[tid];
    for (int k = 0; k < 64; ++k) a += hid[k] * W2[k * 2 + tid];
    out[b * 2 + tid] = a;
  }
}

extern "C" void kernel_launch(void* const* d_in, const int* in_sizes, int n_in,
                              void* d_out, int out_size, void* d_ws, size_t ws_size,
                              hipStream_t stream) {
  const int*   charseqs      = (const int*)d_in[0];
  const int*   charseq_lens  = (const int*)d_in[1];
  const int*   charseq_ids   = (const int*)d_in[2];
  const int*   word_ids      = (const int*)d_in[3];
  const int*   sentence_lens = (const int*)d_in[4];
  const float* char_emb      = (const float*)d_in[5];
  const float* word_emb      = (const float*)d_in[6];
  const float* Wg_c          = (const float*)d_in[7];
  const float* bg_c          = (const float*)d_in[8];
  const float* Wc_c          = (const float*)d_in[9];
  const float* bc_c          = (const float*)d_in[10];
  const float* Wg_w          = (const float*)d_in[11];
  const float* bg_w          = (const float*)d_in[12];
  const float* Wc_w          = (const float*)d_in[13];
  const float* bc_w          = (const float*)d_in[14];
  const float* W1            = (const float*)d_in[15];
  const float* b1            = (const float*)d_in[16];
  const float* W2            = (const float*)d_in[17];
  const float* b2            = (const float*)d_in[18];
  float* out = (float*)d_out;

  float* ws = (float*)d_ws;
  size_t off = 0;
  auto alloc = [&](size_t n) { float* p = ws + off; off += n; return p; };
  float* XTABg = alloc(256 * 1024);
  float* XTABc = alloc(256 * 512);
  float* HcA   = alloc((size_t)4096 * 512);
  float* HcB   = alloc((size_t)4096 * 512);
  float* Gc    = alloc((size_t)4096 * 1024);
  float* CTABg = alloc((size_t)2048 * 1024);
  float* CTABc = alloc((size_t)2048 * 512);
  float* XWg   = alloc((size_t)16384 * 1024);
  float* XWc   = alloc((size_t)16384 * 512);
  float* Hw    = alloc(512 * 512);
  unsigned short* WhgBF = (unsigned short*)alloc(512 * 1024 / 2); // 512K bf16
  unsigned short* WhcBF = (unsigned short*)alloc(512 * 512 / 2);  // 256K bf16

  hipMemsetAsync(HcA, 0, (size_t)4096 * 512 * sizeof(float), stream);

  // --- Stage 0: convert word recurrent weights to bf16 (RNE) ---
  wconv_k<<<(512 * 1024 + 255) / 256, 256, 0, stream>>>(
      Wg_w + (size_t)1280 * 1024, WhgBF, 512 * 1024);
  wconv_k<<<(512 * 512 + 255) / 256, 256, 0, stream>>>(
      Wc_w + (size_t)1280 * 512, WhcBF, 512 * 512);

  // --- Stage A: char x-part tables ---
  {
    GemmArgs a{}; a.M = 256; a.N = 1024; a.K = 128;
    a.A = char_emb; a.lda = 128; a.B = Wg_c; a.bias = bg_c; a.Cout = XTABg; a.ldc = 1024;
    gemm_k<A_PLAIN, E_BIAS><<<dim3(1024 / TILE, 256 / TILE), 256, 0, stream>>>(a);
    GemmArgs c{}; c.M = 256; c.N = 512; c.K = 128;
    c.A = char_emb; c.lda = 128; c.B = Wc_c; c.bias = bc_c; c.Cout = XTABc; c.ldc = 512;
    gemm_k<A_PLAIN, E_BIAS><<<dim3(512 / TILE, 256 / TILE), 256, 0, stream>>>(c);
  }

  // --- Stage B: char bi-GRU GEMM loop (64-tile, fp32) ---
  float* hcur = HcA; float* hnext = HcB;
  for (int t = 0; t < 16; ++t) {
    GemmArgs g{}; g.M = 4096; g.N = 1024; g.K = 512;
    g.A = hcur; g.lda = 512; g.B = Wg_c + 128 * 1024;
    g.XT = XTABg; g.ldxt = 1024; g.seqs = charseqs; g.lens = charseq_lens; g.t = t; g.T = 16;
    g.Cout = Gc; g.ldc = 1024;
    gemm_k<A_PLAIN, E_GATE_CHAR><<<dim3(1024 / TILE, 4096 / TILE), 256, 0, stream>>>(g);

    GemmArgs c{}; c.M = 4096; c.N = 512; c.K = 512;
    c.A = hcur; c.lda = 512; c.G = Gc; c.ldg = 1024; c.B = Wc_c + 128 * 512;
    c.XT = XTABc; c.ldxt = 512; c.seqs = charseqs; c.lens = charseq_lens; c.t = t; c.T = 16;
    c.Hin = hcur; c.Cout = hnext; c.ldc = 512;
    gemm_k<A_RH, E_CAND_CHAR><<<dim3(512 / TILE, 4096 / TILE), 256, 0, stream>>>(c);

    float* tmp = hcur; hcur = hnext; hnext = tmp;
  }
  // after 16 steps hcur == HcA

  // --- Stage C: per-wordform x-part ---
  {
    GemmArgs a{}; a.M = 2048; a.N = 1024; a.K = 1024;
    a.A = hcur; a.B = Wg_w; a.bias = bg_w; a.Cout = CTABg; a.ldc = 1024;
    gemm_k<A_CHARSTATE, E_BIAS><<<dim3(1024 / TILE, 2048 / TILE), 256, 0, stream>>>(a);
    GemmArgs c{}; c.M = 2048; c.N = 512; c.K = 1024;
    c.A = hcur; c.B = Wc_w; c.bias = bc_w; c.Cout = CTABc; c.ldc = 512;
    gemm_k<A_CHARSTATE, E_BIAS><<<dim3(512 / TILE, 2048 / TILE), 256, 0, stream>>>(c);
  }

  // --- Stage D: word-emb x-part + CTAB gather ---
  {
    GemmArgs a{}; a.M = 16384; a.N = 1024; a.K = 256;
    a.A = word_emb; a.lda = 256; a.arows = word_ids; a.B = Wg_w + (size_t)1024 * 1024;
    a.XT = CTABg; a.ldxt = 1024; a.cidx = charseq_ids; a.Cout = XWg; a.ldc = 1024;
    gemm_k<A_GATHER, E_XW><<<dim3(1024 / TILE, 16384 / TILE), 256, 0, stream>>>(a);
    GemmArgs c{}; c.M = 16384; c.N = 512; c.K = 256;
    c.A = word_emb; c.lda = 256; c.arows = word_ids; c.B = Wc_w + (size_t)1024 * 512;
    c.XT = CTABc; c.ldxt = 512; c.cidx = charseq_ids; c.Cout = XWc; c.ldc = 512;
    gemm_k<A_GATHER, E_XW><<<dim3(512 / TILE, 16384 / TILE), 256, 0, stream>>>(c);
  }

  // --- Stage E: fused word bi-GRU, bf16 weights (R=1, 512 blocks x 256 thr) ---
  gru_word_bf<1, 256, 64><<<512, 256, 0, stream>>>(
      WhgBF, WhcBF, XWg, XWc, sentence_lens, Hw);

  // --- Stage F: FC head ---
  head_k<<<256, 64, 0, stream>>>(Hw, W1, b1, W2, b2, out);
}

// Round 15
// 3628.254 us; speedup vs baseline: 1.3887x; 1.3887x over previous
//
#include <hip/hip_runtime.h>
#include <math.h>

// ---------------------------------------------------------------------------
// Hierarchical bi-GRU (char bi-GRU -> word bi-GRU -> FC head).
//
// r15 = r14 resubmitted verbatim (r14 bench died on broker infra, kernel
// never ran): r12 word config (gru_word_bf R=2, 256 blocks -- best measured
// 2376us) + char recurrent GEMMs on bf16 MFMA (mfma_f32_16x16x32_bf16):
// BM=64 tiles, gate BN=128 / cand BN=64 -> 512 blocks each (2/CU),
// h (and r*h) converted fp32->bf16 (RNE) in LDS staging, weights
// pre-converted once. fp32 accumulation; fused sigmoid / tanh+update
// epilogues. Stages A/C/D stay fp32 (64-tile gemm_k).
//
//   gates = sigmoid(x@Wg_x + h@Wg_h + bg)      (x-part precomputed)
//   c     = tanh  (x@Wc_x + (r*h)@Wc_h + bc)
//   h'    = mask ? u*h + (1-u)*c : h
// ---------------------------------------------------------------------------

#define TILE 64
#define BKK 16

typedef __attribute__((ext_vector_type(8))) short bshort8;
typedef __attribute__((ext_vector_type(4))) float f32x4;

enum AMode { A_PLAIN = 0, A_CHARSTATE = 1, A_RH = 2, A_GATHER = 3 };
enum EMode { E_BIAS = 0, E_GATE_CHAR = 1, E_CAND_CHAR = 2, E_XW = 3 };

struct GemmArgs {
  int M, N, K;
  const float* A; int lda;
  const float* G; int ldg;
  const int*   arows;
  const float* B;
  const float* bias;
  const float* XT; int ldxt;
  const int*   seqs;
  const int*   lens;
  int t, T;
  const int*   cidx;
  const float* Hin;
  float* Cout; int ldc;
};

__device__ __forceinline__ float sigmoidf_(float x) { return 1.0f / (1.0f + expf(-x)); }
__device__ __forceinline__ float bf2f_(unsigned short u) {
  return __uint_as_float((unsigned int)u << 16);
}
__device__ __forceinline__ unsigned short f2bf_(float f) {
  const unsigned int u = __float_as_uint(f);
  return (unsigned short)((u + 0x7FFFu + ((u >> 16) & 1u)) >> 16);
}

// --------------------------- fp32 64x64 tile GEMM (stages A, C, D) ----------
template<int AM, int EM>
__global__ __launch_bounds__(256) void gemm_k(GemmArgs p) {
  __shared__ float As[BKK][TILE];
  __shared__ float Bs[BKK][TILE];
  const int tid = threadIdx.x;
  const int tx = tid & 15, ty = tid >> 4;
  const int m0 = blockIdx.y * TILE, n0 = blockIdx.x * TILE;
  const int la_r = tid >> 2, la_k = (tid & 3) << 2;
  const int lb_k = tid >> 4, lb_n = (tid & 15) << 2;

  float acc[4][4] = {};
  int arow = 0;
  if constexpr (AM == A_GATHER) arow = p.arows[m0 + la_r];

  for (int k0 = 0; k0 < p.K; k0 += BKK) {
    float4 av;
    const int m = m0 + la_r;
    const int k = k0 + la_k;
    if constexpr (AM == A_PLAIN) {
      av = *reinterpret_cast<const float4*>(p.A + (size_t)m * p.lda + k);
    } else if constexpr (AM == A_CHARSTATE) {
      const float* ap = (k < 512) ? (p.A + (size_t)m * 512 + k)
                                  : (p.A + (size_t)(2048 + m) * 512 + (k - 512));
      av = *reinterpret_cast<const float4*>(ap);
    } else { // A_GATHER
      av = *reinterpret_cast<const float4*>(p.A + (size_t)arow * p.lda + k);
    }
    As[la_k + 0][la_r] = av.x;
    As[la_k + 1][la_r] = av.y;
    As[la_k + 2][la_r] = av.z;
    As[la_k + 3][la_r] = av.w;
    float4 bv = *reinterpret_cast<const float4*>(p.B + (size_t)(k0 + lb_k) * p.N + n0 + lb_n);
    *reinterpret_cast<float4*>(&Bs[lb_k][lb_n]) = bv;
    __syncthreads();
#pragma unroll
    for (int kk = 0; kk < BKK; ++kk) {
      float4 a = *reinterpret_cast<const float4*>(&As[kk][ty << 2]);
      float4 b = *reinterpret_cast<const float4*>(&Bs[kk][tx << 2]);
      acc[0][0] += a.x * b.x; acc[0][1] += a.x * b.y; acc[0][2] += a.x * b.z; acc[0][3] += a.x * b.w;
      acc[1][0] += a.y * b.x; acc[1][1] += a.y * b.y; acc[1][2] += a.y * b.z; acc[1][3] += a.y * b.w;
      acc[2][0] += a.z * b.x; acc[2][1] += a.z * b.y; acc[2][2] += a.z * b.z; acc[2][3] += a.z * b.w;
      acc[3][0] += a.w * b.x; acc[3][1] += a.w * b.y; acc[3][2] += a.w * b.z; acc[3][3] += a.w * b.w;
    }
    __syncthreads();
  }

  const int rbase = m0 + (ty << 2);
  const int cbase = n0 + (tx << 2);
#pragma unroll
  for (int i = 0; i < 4; ++i) {
    const int row = rbase + i;
    if constexpr (EM == E_BIAS) {
#pragma unroll
      for (int j = 0; j < 4; ++j) {
        const int col = cbase + j;
        p.Cout[(size_t)row * p.ldc + col] = acc[i][j] + p.bias[col];
      }
    } else { // E_XW
      const int cs = p.cidx[row];
      const float* xrow = p.XT + (size_t)cs * p.ldxt;
#pragma unroll
      for (int j = 0; j < 4; ++j) {
        const int col = cbase + j;
        p.Cout[(size_t)row * p.ldc + col] = acc[i][j] + xrow[col];
      }
    }
  }
}

// fp32 -> bf16 (RNE) weight conversion
__global__ __launch_bounds__(256) void wconv_k(const float* __restrict__ src,
                                               unsigned short* __restrict__ dst,
                                               int n) {
  const int i = blockIdx.x * 256 + threadIdx.x;
  if (i < n) dst[i] = f2bf_(src[i]);
}

// ---------------------------------------------------------------------------
// Char recurrent GEMM via bf16 MFMA. BM=64 rows, BN cols (gate 128, cand 64),
// BK=32, 256 threads = 4 waves (wave w owns cols [w*BN/4, ...)).
// EM: 0 = gate (A = hcur; out = sigmoid -> Gc), 1 = cand (A = r*h; out =
// tanh + masked h-update -> hnext).
// A staged fp32->bf16 in LDS [64][40] (pad 40 for bank spread); B (bf16
// weights) staged transposed [BN][40] so b-frag reads are contiguous.
// Fragment maps: A row=lane&15, k=8*(lane>>4)+j; B col=lane&15, same k;
// D col=lane&15, row=(lane>>4)*4+reg (m89-verified).
// ---------------------------------------------------------------------------
template<int BN, int EM>
__global__ __launch_bounds__(256) void cgemm_mfma(
    const float* __restrict__ Ain,        // hcur [4096][512]
    const float* __restrict__ G,          // EM=1: Gc [4096][1024]
    const unsigned short* __restrict__ Bw,// bf16 weights [512][ldb]
    int ldb,
    const float* __restrict__ XT,         // x-part table (256 rows)
    const int* __restrict__ seqs,         // [2048][16]
    const int* __restrict__ lens,         // [2048]
    int t,
    const float* __restrict__ Hin,        // EM=1: hcur
    float* __restrict__ Cout, int ldc) {
  __shared__ unsigned short As[64][40];
  __shared__ unsigned short Bs[BN][40];
  __shared__ int xo_s[64];
  __shared__ int msk_s[64];

  const int tid = threadIdx.x;
  const int m0 = blockIdx.y * 64;
  const int n0 = blockIdx.x * BN;

  // per-row step context
  if (tid < 64) {
    const int grow = m0 + tid;
    const int us = grow & 2047;
    const bool dir = grow >= 2048;
    const int len = lens[us];
    int pos = dir ? (len - 1 - t) : t;
    pos = pos < 0 ? 0 : (pos > 15 ? 15 : pos);
    const int ch = seqs[us * 16 + pos];
    xo_s[tid] = ch * ((EM == 0) ? 1024 : 512);
    msk_s[tid] = (t < len) ? 1 : 0;
  }

  const int wid = tid >> 6, lane = tid & 63;
  const int lr = lane & 15, lk = (lane >> 4) << 3;
  constexpr int NI = BN / 64;              // fragments per wave in N
  const int c0w = wid * (BN / 4);

  f32x4 acc[4][NI];
#pragma unroll
  for (int mi = 0; mi < 4; ++mi)
#pragma unroll
    for (int ni = 0; ni < NI; ++ni) acc[mi][ni] = (f32x4){0.f, 0.f, 0.f, 0.f};

  const int arow = tid >> 2;               // A staging: 0..63
  const int akoff = (tid & 3) << 3;        // 0,8,16,24

  for (int k0 = 0; k0 < 512; k0 += 32) {
    // ---- stage A (fp32 -> bf16) ----
    {
      const float* ap = Ain + (size_t)(m0 + arow) * 512 + k0 + akoff;
      float4 a0 = *reinterpret_cast<const float4*>(ap);
      float4 a1 = *reinterpret_cast<const float4*>(ap + 4);
      if constexpr (EM == 1) {  // A = r * h
        const float* gp = G + (size_t)(m0 + arow) * 1024 + k0 + akoff;
        float4 g0 = *reinterpret_cast<const float4*>(gp);
        float4 g1 = *reinterpret_cast<const float4*>(gp + 4);
        a0.x *= g0.x; a0.y *= g0.y; a0.z *= g0.z; a0.w *= g0.w;
        a1.x *= g1.x; a1.y *= g1.y; a1.z *= g1.z; a1.w *= g1.w;
      }
      bshort8 av;
      av[0] = (short)f2bf_(a0.x); av[1] = (short)f2bf_(a0.y);
      av[2] = (short)f2bf_(a0.z); av[3] = (short)f2bf_(a0.w);
      av[4] = (short)f2bf_(a1.x); av[5] = (short)f2bf_(a1.y);
      av[6] = (short)f2bf_(a1.z); av[7] = (short)f2bf_(a1.w);
      *reinterpret_cast<bshort8*>(&As[arow][akoff]) = av;
    }
    // ---- stage B transposed ----
    if (BN == 128 || tid < 128) {
      const int bc0 = (BN == 128) ? ((tid & 31) << 2) : ((tid & 15) << 2);
      const int bk0 = (BN == 128) ? ((tid >> 5) << 2) : ((tid >> 4) << 2);
      ushort4 b0 = *reinterpret_cast<const ushort4*>(Bw + (size_t)(k0 + bk0 + 0) * ldb + n0 + bc0);
      ushort4 b1 = *reinterpret_cast<const ushort4*>(Bw + (size_t)(k0 + bk0 + 1) * ldb + n0 + bc0);
      ushort4 b2 = *reinterpret_cast<const ushort4*>(Bw + (size_t)(k0 + bk0 + 2) * ldb + n0 + bc0);
      ushort4 b3 = *reinterpret_cast<const ushort4*>(Bw + (size_t)(k0 + bk0 + 3) * ldb + n0 + bc0);
      ushort4 w;
      w.x = b0.x; w.y = b1.x; w.z = b2.x; w.w = b3.x;
      *reinterpret_cast<ushort4*>(&Bs[bc0 + 0][bk0]) = w;
      w.x = b0.y; w.y = b1.y; w.z = b2.y; w.w = b3.y;
      *reinterpret_cast<ushort4*>(&Bs[bc0 + 1][bk0]) = w;
      w.x = b0.z; w.y = b1.z; w.z = b2.z; w.w = b3.z;
      *reinterpret_cast<ushort4*>(&Bs[bc0 + 2][bk0]) = w;
      w.x = b0.w; w.y = b1.w; w.z = b2.w; w.w = b3.w;
      *reinterpret_cast<ushort4*>(&Bs[bc0 + 3][bk0]) = w;
    }
    __syncthreads();

    // ---- fragments + MFMA ----
    bshort8 af[4];
#pragma unroll
    for (int mi = 0; mi < 4; ++mi)
      af[mi] = *reinterpret_cast<const bshort8*>(&As[mi * 16 + lr][lk]);
#pragma unroll
    for (int ni = 0; ni < NI; ++ni) {
      const bshort8 bf = *reinterpret_cast<const bshort8*>(&Bs[c0w + ni * 16 + lr][lk]);
#pragma unroll
      for (int mi = 0; mi < 4; ++mi)
        acc[mi][ni] = __builtin_amdgcn_mfma_f32_16x16x32_bf16(af[mi], bf, acc[mi][ni], 0, 0, 0);
    }
    __syncthreads();
  }

  // ---- epilogue ----
  const int rq = lane >> 4;
#pragma unroll
  for (int mi = 0; mi < 4; ++mi) {
#pragma unroll
    for (int ni = 0; ni < NI; ++ni) {
#pragma unroll
      for (int reg = 0; reg < 4; ++reg) {
        const int lrow = mi * 16 + rq * 4 + reg;
        const int grow = m0 + lrow;
        const int col = n0 + c0w + ni * 16 + lr;
        const float v = acc[mi][ni][reg];
        if constexpr (EM == 0) {
          Cout[(size_t)grow * ldc + col] = sigmoidf_(v + XT[xo_s[lrow] + col]);
        } else {
          const float cv = tanhf(v + XT[xo_s[lrow] + col]);
          const float u = G[(size_t)grow * 1024 + 512 + col];
          const float h = Hin[(size_t)grow * 512 + col];
          Cout[(size_t)grow * ldc + col] = msk_s[lrow] ? (u * h + (1.0f - u) * cv) : h;
        }
      }
    }
  }
}

// ---------------------------------------------------------------------------
// Fused persistent word GRU, bf16 weights (r12 config: R=2, 256 blocks x 256).
// ---------------------------------------------------------------------------
template<int R, int NU, int TT>
__global__ __launch_bounds__(256) void gru_word_bf(
    const unsigned short* __restrict__ Whg,  // [512,1024] bf16
    const unsigned short* __restrict__ Whc,  // [512,512]  bf16
    const float* __restrict__ Xg,            // [NU*TT,1024] (bias folded)
    const float* __restrict__ Xc,            // [NU*TT,512]
    const int*   __restrict__ lens,          // [NU]
    float* __restrict__ Hout)                // [2*NU, 512]
{
  __shared__ float h_s [R][512];
  __shared__ float rh_s[R][512];
  __shared__ float u_s [R][512];
  __shared__ int   xog_s[R];
  __shared__ int   xoc_s[R];
  __shared__ int   msk_s[R];

  const int tid  = threadIdx.x;
  const int row0 = blockIdx.x * R;
  const int us0  = row0 & (NU - 1);
  const bool bw  = row0 >= NU;

  for (int i = tid; i < R * 512; i += 256) h_s[i >> 9][i & 511] = 0.0f;
  int mylen = 0;
  if (tid < R) mylen = lens[us0 + tid];
  __syncthreads();

  const int c0 = tid << 2;
  const int c2 = tid << 1;

  for (int t = 0; t < TT; ++t) {
    if (tid < R) {
      int pos = bw ? (mylen - 1 - t) : t;
      pos = pos < 0 ? 0 : (pos > TT - 1 ? TT - 1 : pos);
      const int xr = (us0 + tid) * TT + pos;
      xog_s[tid] = xr * 1024;
      xoc_s[tid] = xr * 512;
      msk_s[tid] = (t < mylen) ? 1 : 0;
    }
    __syncthreads();

    float4 acc[R];
#pragma unroll
    for (int r = 0; r < R; ++r) acc[r] = make_float4(0.f, 0.f, 0.f, 0.f);
#pragma unroll 2
    for (int k0 = 0; k0 < 512; k0 += 4) {
      ushort4 wu[4];
#pragma unroll
      for (int i = 0; i < 4; ++i)
        wu[i] = *reinterpret_cast<const ushort4*>(Whg + (size_t)(k0 + i) * 1024 + c0);
      float4 hv[R];
#pragma unroll
      for (int r = 0; r < R; ++r)
        hv[r] = *reinterpret_cast<const float4*>(&h_s[r][k0]);
#pragma unroll
      for (int i = 0; i < 4; ++i) {
        const float wx = bf2f_(wu[i].x), wy = bf2f_(wu[i].y);
        const float wz = bf2f_(wu[i].z), ww = bf2f_(wu[i].w);
#pragma unroll
        for (int r = 0; r < R; ++r) {
          const float h = (i == 0) ? hv[r].x : (i == 1) ? hv[r].y : (i == 2) ? hv[r].z : hv[r].w;
          acc[r].x += h * wx; acc[r].y += h * wy;
          acc[r].z += h * wz; acc[r].w += h * ww;
        }
      }
    }
#pragma unroll
    for (int r = 0; r < R; ++r) {
      const float4 x = *reinterpret_cast<const float4*>(Xg + xog_s[r] + c0);
      float4 g;
      g.x = sigmoidf_(acc[r].x + x.x);
      g.y = sigmoidf_(acc[r].y + x.y);
      g.z = sigmoidf_(acc[r].z + x.z);
      g.w = sigmoidf_(acc[r].w + x.w);
      if (c0 < 512) {
        const float4 hh = *reinterpret_cast<const float4*>(&h_s[r][c0]);
        rh_s[r][c0 + 0] = g.x * hh.x;
        rh_s[r][c0 + 1] = g.y * hh.y;
        rh_s[r][c0 + 2] = g.z * hh.z;
        rh_s[r][c0 + 3] = g.w * hh.w;
      } else {
        u_s[r][c0 - 512 + 0] = g.x;
        u_s[r][c0 - 512 + 1] = g.y;
        u_s[r][c0 - 512 + 2] = g.z;
        u_s[r][c0 - 512 + 3] = g.w;
      }
    }
    __syncthreads();

    float2 acc2[R];
#pragma unroll
    for (int r = 0; r < R; ++r) acc2[r] = make_float2(0.f, 0.f);
#pragma unroll 2
    for (int k0 = 0; k0 < 512; k0 += 4) {
      ushort2 wu[4];
#pragma unroll
      for (int i = 0; i < 4; ++i)
        wu[i] = *reinterpret_cast<const ushort2*>(Whc + (size_t)(k0 + i) * 512 + c2);
      float4 rv[R];
#pragma unroll
      for (int r = 0; r < R; ++r)
        rv[r] = *reinterpret_cast<const float4*>(&rh_s[r][k0]);
#pragma unroll
      for (int i = 0; i < 4; ++i) {
        const float wx = bf2f_(wu[i].x), wy = bf2f_(wu[i].y);
#pragma unroll
        for (int r = 0; r < R; ++r) {
          const float rvv = (i == 0) ? rv[r].x : (i == 1) ? rv[r].y : (i == 2) ? rv[r].z : rv[r].w;
          acc2[r].x += rvv * wx; acc2[r].y += rvv * wy;
        }
      }
    }
#pragma unroll
    for (int r = 0; r < R; ++r) {
      const float2 x = *reinterpret_cast<const float2*>(Xc + xoc_s[r] + c2);
      const float cx = tanhf(acc2[r].x + x.x);
      const float cy = tanhf(acc2[r].y + x.y);
      if (msk_s[r]) {
        const float ux = u_s[r][c2], uy = u_s[r][c2 + 1];
        const float hx = h_s[r][c2], hy = h_s[r][c2 + 1];
        h_s[r][c2]     = ux * hx + (1.0f - ux) * cx;
        h_s[r][c2 + 1] = uy * hy + (1.0f - uy) * cy;
      }
    }
    __syncthreads();
  }

  for (int i = tid; i < R * 512; i += 256)
    Hout[(size_t)(row0 + (i >> 9)) * 512 + (i & 511)] = h_s[i >> 9][i & 511];
}

// FC head
__global__ __launch_bounds__(64) void head_k(const float* __restrict__ Hw,
                                             const float* __restrict__ W1,
                                             const float* __restrict__ b1,
                                             const float* __restrict__ W2,
                                             const float* __restrict__ b2,
                                             float* __restrict__ out) {
  __shared__ float s[1024];
  __shared__ float hid[64];
  const int b = blockIdx.x;
  const int tid = threadIdx.x;
  for (int k = tid; k < 512; k += 64) {
    s[k]       = Hw[(size_t)b * 512 + k];
    s[512 + k] = Hw[(size_t)(256 + b) * 512 + k];
  }
  __syncthreads();
  float acc = b1[tid];
  for (int k = 0; k < 1024; ++k) acc += s[k] * W1[k * 64 + tid];
  acc = acc > 0.0f ? acc : 0.2f * acc;
  hid[tid] = acc;
  __syncthreads();
  if (tid < 2) {
    float a = b2[tid];
    for (int k = 0; k < 64; ++k) a += hid[k] * W2[k * 2 + tid];
    out[b * 2 + tid] = a;
  }
}

extern "C" void kernel_launch(void* const* d_in, const int* in_sizes, int n_in,
                              void* d_out, int out_size, void* d_ws, size_t ws_size,
                              hipStream_t stream) {
  const int*   charseqs      = (const int*)d_in[0];
  const int*   charseq_lens  = (const int*)d_in[1];
  const int*   charseq_ids   = (const int*)d_in[2];
  const int*   word_ids      = (const int*)d_in[3];
  const int*   sentence_lens = (const int*)d_in[4];
  const float* char_emb      = (const float*)d_in[5];
  const float* word_emb      = (const float*)d_in[6];
  const float* Wg_c          = (const float*)d_in[7];
  const float* bg_c          = (const float*)d_in[8];
  const float* Wc_c          = (const float*)d_in[9];
  const float* bc_c          = (const float*)d_in[10];
  const float* Wg_w          = (const float*)d_in[11];
  const float* bg_w          = (const float*)d_in[12];
  const float* Wc_w          = (const float*)d_in[13];
  const float* bc_w          = (const float*)d_in[14];
  const float* W1            = (const float*)d_in[15];
  const float* b1            = (const float*)d_in[16];
  const float* W2            = (const float*)d_in[17];
  const float* b2            = (const float*)d_in[18];
  float* out = (float*)d_out;

  float* ws = (float*)d_ws;
  size_t off = 0;
  auto alloc = [&](size_t n) { float* p = ws + off; off += n; return p; };
  float* XTABg = alloc(256 * 1024);
  float* XTABc = alloc(256 * 512);
  float* HcA   = alloc((size_t)4096 * 512);
  float* HcB   = alloc((size_t)4096 * 512);
  float* Gc    = alloc((size_t)4096 * 1024);
  float* CTABg = alloc((size_t)2048 * 1024);
  float* CTABc = alloc((size_t)2048 * 512);
  float* XWg   = alloc((size_t)16384 * 1024);
  float* XWc   = alloc((size_t)16384 * 512);
  float* Hw    = alloc(512 * 512);
  unsigned short* WhgBF = (unsigned short*)alloc(512 * 1024 / 2); // word gate W
  unsigned short* WhcBF = (unsigned short*)alloc(512 * 512 / 2);  // word cand W
  unsigned short* WgcBF = (unsigned short*)alloc(512 * 1024 / 2); // char gate W
  unsigned short* WccBF = (unsigned short*)alloc(512 * 512 / 2);  // char cand W

  hipMemsetAsync(HcA, 0, (size_t)4096 * 512 * sizeof(float), stream);

  // --- Stage 0: bf16 weight conversions (word + char h-parts) ---
  wconv_k<<<(512 * 1024 + 255) / 256, 256, 0, stream>>>(
      Wg_w + (size_t)1280 * 1024, WhgBF, 512 * 1024);
  wconv_k<<<(512 * 512 + 255) / 256, 256, 0, stream>>>(
      Wc_w + (size_t)1280 * 512, WhcBF, 512 * 512);
  wconv_k<<<(512 * 1024 + 255) / 256, 256, 0, stream>>>(
      Wg_c + 128 * 1024, WgcBF, 512 * 1024);
  wconv_k<<<(512 * 512 + 255) / 256, 256, 0, stream>>>(
      Wc_c + 128 * 512, WccBF, 512 * 512);

  // --- Stage A: char x-part tables (fp32) ---
  {
    GemmArgs a{}; a.M = 256; a.N = 1024; a.K = 128;
    a.A = char_emb; a.lda = 128; a.B = Wg_c; a.bias = bg_c; a.Cout = XTABg; a.ldc = 1024;
    gemm_k<A_PLAIN, E_BIAS><<<dim3(1024 / TILE, 256 / TILE), 256, 0, stream>>>(a);
    GemmArgs c{}; c.M = 256; c.N = 512; c.K = 128;
    c.A = char_emb; c.lda = 128; c.B = Wc_c; c.bias = bc_c; c.Cout = XTABc; c.ldc = 512;
    gemm_k<A_PLAIN, E_BIAS><<<dim3(512 / TILE, 256 / TILE), 256, 0, stream>>>(c);
  }

  // --- Stage B: char bi-GRU, MFMA bf16 GEMM loop ---
  float* hcur = HcA; float* hnext = HcB;
  for (int t = 0; t < 16; ++t) {
    // gate: [4096,1024] = hcur @ WgcBF, sigmoid epilogue -> Gc
    cgemm_mfma<128, 0><<<dim3(1024 / 128, 4096 / 64), 256, 0, stream>>>(
        hcur, nullptr, WgcBF, 1024, XTABg, charseqs, charseq_lens, t, nullptr,
        Gc, 1024);
    // cand: [4096,512] = (r*h) @ WccBF, tanh + masked update -> hnext
    cgemm_mfma<64, 1><<<dim3(512 / 64, 4096 / 64), 256, 0, stream>>>(
        hcur, Gc, WccBF, 512, XTABc, charseqs, charseq_lens, t, hcur,
        hnext, 512);
    float* tmp = hcur; hcur = hnext; hnext = tmp;
  }
  // after 16 steps hcur == HcA

  // --- Stage C: per-wordform x-part (fp32) ---
  {
    GemmArgs a{}; a.M = 2048; a.N = 1024; a.K = 1024;
    a.A = hcur; a.B = Wg_w; a.bias = bg_w; a.Cout = CTABg; a.ldc = 1024;
    gemm_k<A_CHARSTATE, E_BIAS><<<dim3(1024 / TILE, 2048 / TILE), 256, 0, stream>>>(a);
    GemmArgs c{}; c.M = 2048; c.N = 512; c.K = 1024;
    c.A = hcur; c.B = Wc_w; c.bias = bc_w; c.Cout = CTABc; c.ldc = 512;
    gemm_k<A_CHARSTATE, E_BIAS><<<dim3(512 / TILE, 2048 / TILE), 256, 0, stream>>>(c);
  }

  // --- Stage D: word-emb x-part + CTAB gather (fp32) ---
  {
    GemmArgs a{}; a.M = 16384; a.N = 1024; a.K = 256;
    a.A = word_emb; a.lda = 256; a.arows = word_ids; a.B = Wg_w + (size_t)1024 * 1024;
    a.XT = CTABg; a.ldxt = 1024; a.cidx = charseq_ids; a.Cout = XWg; a.ldc = 1024;
    gemm_k<A_GATHER, E_XW><<<dim3(1024 / TILE, 16384 / TILE), 256, 0, stream>>>(a);
    GemmArgs c{}; c.M = 16384; c.N = 512; c.K = 256;
    c.A = word_emb; c.lda = 256; c.arows = word_ids; c.B = Wc_w + (size_t)1024 * 512;
    c.XT = CTABc; c.ldxt = 512; c.cidx = charseq_ids; c.Cout = XWc; c.ldc = 512;
    gemm_k<A_GATHER, E_XW><<<dim3(512 / TILE, 16384 / TILE), 256, 0, stream>>>(c);
  }

  // --- Stage E: fused word bi-GRU, bf16 weights (R=2, 256 blocks, r12 cfg) ---
  gru_word_bf<2, 256, 64><<<256, 256, 0, stream>>>(
      WhgBF, WhcBF, XWg, XWc, sentence_lens, Hw);

  // --- Stage F: FC head ---
  head_k<<<256, 64, 0, stream>>>(Hw, W1, b1, W2, b2, out);
}